// Round 13
// baseline (154.227 us; speedup 1.0000x reference)
//
#include <hip/hip_runtime.h>

#define NNODES 100000
#define NEDGES 1600000
#define DFEAT  128
#define NPOOL  25000

#define NG 128                                       // partition groups
#define GSPAN ((NNODES + NG - 1) / NG)               // 782 nodes per group (128*782=100096)
#define GCAP 14080                                   // per-group bucket cap (E=12500, sigma~111 -> 14 sigma)
#define CONVB 256                                    // convert-role blocks fused into group kernel

// bf16 RNE helpers (manual, deterministic)
__device__ __forceinline__ unsigned int f2bf(float f) {
    unsigned int b = __float_as_uint(f);
    return (b + 0x7fffu + ((b >> 16) & 1u)) >> 16;
}
__device__ __forceinline__ float bf2f_lo(unsigned int packed) {
    return __uint_as_float(packed << 16);
}
__device__ __forceinline__ float bf2f_hi(unsigned int packed) {
    return __uint_as_float(packed & 0xffff0000u);
}

// ---------------- CSR build, phase P: partition into 128 groups ---------------
// 256-thread blocks, 4 edges/thread (one int4/float4 per array). Slot via LDS
// atomics over 128 counters; per-block contiguous runs reserved in gcur.
// Record packs {dst_local(10b) << 17 | src(17b)} and w bits.
__global__ __launch_bounds__(256) void part_kernel(const int* __restrict__ dst,
                                                   const int* __restrict__ src,
                                                   const float* __restrict__ w,
                                                   int* __restrict__ gcur,
                                                   int2* __restrict__ bkt) {
    __shared__ int lhist[NG];
    __shared__ int lbase[NG];
    const int n4 = NEDGES / 4;
    int i = blockIdx.x * blockDim.x + threadIdx.x;
    bool active = (i < n4);
    int4 d4 = make_int4(0, 0, 0, 0);
    int4 s4 = make_int4(0, 0, 0, 0);
    float4 w4 = make_float4(0.f, 0.f, 0.f, 0.f);
    if (active) {
        d4 = ((const int4*)dst)[i];
        s4 = ((const int4*)src)[i];
        w4 = ((const float4*)w)[i];
    }
    if (threadIdx.x < NG) lhist[threadIdx.x] = 0;
    __syncthreads();
    int dv[4] = {d4.x, d4.y, d4.z, d4.w};
    int sv[4] = {s4.x, s4.y, s4.z, s4.w};
    float wv[4] = {w4.x, w4.y, w4.z, w4.w};
    int gk[4], slot[4];
    #pragma unroll
    for (int k = 0; k < 4; ++k) {
        gk[k] = dv[k] / GSPAN;
        slot[k] = active ? atomicAdd(&lhist[gk[k]], 1) : 0;
    }
    __syncthreads();
    if (threadIdx.x < NG)
        lbase[threadIdx.x] = atomicAdd(&gcur[threadIdx.x], lhist[threadIdx.x]);
    __syncthreads();
    if (active) {
        #pragma unroll
        for (int k = 0; k < 4; ++k) {
            int g = gk[k];
            int dst_local = dv[k] - g * GSPAN;       // < 782, fits 10 bits
            int idx = g * GCAP + lbase[g] + slot[k];
            bkt[idx] = make_int2(sv[k] | (dst_local << 17), __float_as_int(wv[k]));
        }
    }
}

// ---------------- phase G (+ fused convert) -----------------------------------
// Blocks [0,NG): per-group LDS hist + scan + scatter (zero global atomics).
// Blocks [NG, NG+CONVB): grid-stride convert x(f32) -> xh(bf16) — independent
// work that fills the CUs the 128 group blocks leave idle.
__global__ __launch_bounds__(1024) void group_conv_kernel(const int2* __restrict__ bkt,
                                                          const int* __restrict__ gcur,
                                                          int* __restrict__ rowptr,
                                                          int2* __restrict__ csr_sw,
                                                          const float* __restrict__ x,
                                                          unsigned int* __restrict__ xh_u32) {
    if (blockIdx.x >= NG) {
        // ---- convert role ----
        const int n8 = NNODES * DFEAT / 8;
        int i = (blockIdx.x - NG) * 1024 + threadIdx.x;
        const int stride = CONVB * 1024;
        for (; i < n8; i += stride) {
            float4 a = ((const float4*)x)[i * 2 + 0];
            float4 b = ((const float4*)x)[i * 2 + 1];
            uint4 o;
            o.x = f2bf(a.x) | (f2bf(a.y) << 16);
            o.y = f2bf(a.z) | (f2bf(a.w) << 16);
            o.z = f2bf(b.x) | (f2bf(b.y) << 16);
            o.w = f2bf(b.z) | (f2bf(b.w) << 16);
            ((uint4*)xh_u32)[i] = o;
        }
        return;
    }
    // ---- group role ----
    __shared__ int h[GSPAN];          // hist -> cursor (global positions)
    __shared__ int scanbuf[1024];
    __shared__ int sh_gstart;
    int g = blockIdx.x;
    int tid = threadIdx.x;
    if (tid == 0) {
        int s = 0;
        for (int i = 0; i < g; ++i) s += gcur[i];
        sh_gstart = s;
    }
    if (tid < GSPAN) h[tid] = 0;
    __syncthreads();
    int n = gcur[g];
    const int2* b = bkt + (size_t)g * GCAP;
    for (int j = tid; j < n; j += 1024) {
        atomicAdd(&h[((unsigned)b[j].x) >> 17], 1);
    }
    __syncthreads();
    int v = (tid < GSPAN) ? h[tid] : 0;
    scanbuf[tid] = v;
    __syncthreads();
    for (int off = 1; off < 1024; off <<= 1) {
        int u = (tid >= off) ? scanbuf[tid - off] : 0;
        __syncthreads();
        scanbuf[tid] += u;
        __syncthreads();
    }
    int gstart = sh_gstart;
    int incl = scanbuf[tid];
    if (tid < GSPAN) {
        h[tid] = gstart + incl - v;                  // cursor = row start (global)
        int node = g * GSPAN + tid;
        if (node < NNODES) rowptr[node] = gstart + incl;  // END pointer
    }
    __syncthreads();
    for (int j = tid; j < n; j += 1024) {
        int2 rec = b[j];
        int dl = ((unsigned)rec.x) >> 17;
        int pos = atomicAdd(&h[dl], 1);
        csr_sw[pos] = make_int2(rec.x & 0x1FFFF, rec.y);
    }
}

// ---------------- aggregation ----------------
// After build: row t spans [ t ? rowptr[t-1] : 0 , rowptr[t] ).

__device__ __forceinline__ void agg_row_bf16(const unsigned int* __restrict__ xh,
                                             const int2* __restrict__ csr_sw,
                                             int beg, int end, int lane,
                                             float2& acc) {
    for (int base = beg; base < end; base += 64) {
        int cnt = end - base; if (cnt > 64) cnt = 64;
        int2 sw = make_int2(0, 0);
        if (lane < cnt) sw = csr_sw[base + lane];
        int   my_s = sw.x;
        float my_w = __int_as_float(sw.y);
        int d = 0;
        for (; d + 8 <= cnt; d += 8) {
            int s[8]; float wv[8]; unsigned int v[8];
            #pragma unroll
            for (int k = 0; k < 8; ++k) {
                s[k]  = __shfl(my_s, d + k);
                wv[k] = __shfl(my_w, d + k);
            }
            #pragma unroll
            for (int k = 0; k < 8; ++k) v[k] = xh[(size_t)s[k] * 64 + lane];
            #pragma unroll
            for (int k = 0; k < 8; ++k) {
                acc.x += bf2f_lo(v[k]) * wv[k];
                acc.y += bf2f_hi(v[k]) * wv[k];
            }
        }
        for (; d + 4 <= cnt; d += 4) {
            int s[4]; float wv[4]; unsigned int v[4];
            #pragma unroll
            for (int k = 0; k < 4; ++k) {
                s[k]  = __shfl(my_s, d + k);
                wv[k] = __shfl(my_w, d + k);
            }
            #pragma unroll
            for (int k = 0; k < 4; ++k) v[k] = xh[(size_t)s[k] * 64 + lane];
            #pragma unroll
            for (int k = 0; k < 4; ++k) {
                acc.x += bf2f_lo(v[k]) * wv[k];
                acc.y += bf2f_hi(v[k]) * wv[k];
            }
        }
        for (; d < cnt; ++d) {
            int   s = __shfl(my_s, d);
            float wv = __shfl(my_w, d);
            unsigned int v = xh[(size_t)s * 64 + lane];
            acc.x += bf2f_lo(v) * wv;
            acc.y += bf2f_hi(v) * wv;
        }
    }
}

// hop 1: x1h[n] = bf16( xh[n] + sum_e xh[src_e] * w_e )
__global__ __launch_bounds__(256) void agg1_kernel(const unsigned int* __restrict__ xh,
                                                   const int2* __restrict__ csr_sw,
                                                   const int* __restrict__ rowptr,
                                                   unsigned int* __restrict__ x1h) {
    int gid = blockIdx.x * blockDim.x + threadIdx.x;
    int node = gid >> 6;
    if (node >= NNODES) return;
    int lane = threadIdx.x & 63;
    int beg = node ? rowptr[node - 1] : 0;
    int end = rowptr[node];
    unsigned int r = xh[(size_t)node * 64 + lane];   // residual
    float2 acc = make_float2(bf2f_lo(r), bf2f_hi(r));
    agg_row_bf16(xh, csr_sw, beg, end, lane, acc);
    x1h[(size_t)node * 64 + lane] = f2bf(acc.x) | (f2bf(acc.y) << 16);
}

// hop 2: out[row] = x1h[sel] + sum_e x1h[src_e] * w_e   (f32 output)
__global__ __launch_bounds__(256) void agg2_kernel(const unsigned int* __restrict__ x1h,
                                                   const int2* __restrict__ csr_sw,
                                                   const int* __restrict__ rowptr,
                                                   const int* __restrict__ sel,
                                                   float* __restrict__ out) {
    int gid = blockIdx.x * blockDim.x + threadIdx.x;
    int row = gid >> 6;
    if (row >= NPOOL) return;
    int lane = threadIdx.x & 63;
    int node = sel[row];
    int beg = node ? rowptr[node - 1] : 0;
    int end = rowptr[node];
    unsigned int r = x1h[(size_t)node * 64 + lane];  // residual
    float2 acc = make_float2(bf2f_lo(r), bf2f_hi(r));
    agg_row_bf16(x1h, csr_sw, beg, end, lane, acc);
    ((float2*)out)[(size_t)row * 64 + lane] = acc;
}

// ---------------- launch ----------------

extern "C" void kernel_launch(void* const* d_in, const int* in_sizes, int n_in,
                              void* d_out, int out_size, void* d_ws, size_t ws_size,
                              hipStream_t stream) {
    const float* x         = (const float*)d_in[0];            // [NNODES, DFEAT]
    const float* edge_attr = (const float*)d_in[1];            // [NEDGES]
    const int*   edge_idx  = (const int*)d_in[2];              // [2, NEDGES]
    const int*   sel       = (const int*)d_in[3];              // [NPOOL]
    const int*   src = edge_idx;
    const int*   dst = edge_idx + NEDGES;
    float* out = (float*)d_out;

    // workspace layout: 25.6 + 25.6 + 0.4 + 12.8 + tiny = 64.4 MB (proven budget)
    char* ws = (char*)d_ws;
    unsigned int* xh  = (unsigned int*)ws;  ws += (size_t)NNODES * 64 * sizeof(unsigned int); // 25.6 MB
    char* scratch = ws;                     ws += (size_t)NNODES * 64 * sizeof(unsigned int); // 25.6 MB (x1h)
    int*   rowptr   = (int*)ws;    ws += (size_t)NNODES * sizeof(int);            // 0.4 MB
    int2*  csr_sw   = (int2*)ws;   ws += (size_t)NEDGES * sizeof(int2);           // 12.8 MB
    int*   gcur     = (int*)ws;    ws += (size_t)NG * sizeof(int);

    // bucket scratch aliases x1h (buckets dead before agg1 writes x1h)
    unsigned int* x1h = (unsigned int*)scratch;
    int2* bkt = (int2*)scratch;                                  // 128*14080*8B = 14.4 MB

    hipMemsetAsync(gcur, 0, (size_t)NG * sizeof(int), stream);

    // 1) phase P: partition into 128 group buckets
    {
        int blocks = (NEDGES / 4 + 255) / 256;
        part_kernel<<<blocks, 256, 0, stream>>>(dst, src, edge_attr, gcur, bkt);
    }
    // 2) phase G (+ fused convert on otherwise-idle CUs)
    group_conv_kernel<<<NG + CONVB, 1024, 0, stream>>>(bkt, gcur, rowptr, csr_sw, x, xh);

    // 3) hop 1 (all nodes), bf16 gather, bf16 store
    {
        long long threads = (long long)NNODES * 64;
        int blocks = (int)((threads + 255) / 256);
        agg1_kernel<<<blocks, 256, 0, stream>>>(xh, csr_sw, rowptr, x1h);
    }
    // 4) hop 2 (selected rows only), bf16 gather, f32 out
    {
        long long threads = (long long)NPOOL * 64;
        int blocks = (int)((threads + 255) / 256);
        agg2_kernel<<<blocks, 256, 0, stream>>>(x1h, csr_sw, rowptr, sel, out);
    }
}

// Round 14
// 137.625 us; speedup vs baseline: 1.1206x; 1.1206x over previous
//
#include <hip/hip_runtime.h>

#define NNODES 100000
#define NEDGES 1600000
#define DFEAT  128
#define NPOOL  25000

#define NG 128                                       // partition groups
#define GSPAN ((NNODES + NG - 1) / NG)               // 782 nodes per group (128*782=100096)
#define GCAP 14080                                   // per-group bucket cap (E=12500, sigma~111 -> 14 sigma)
#define PBLOCKS ((NEDGES / 4 + 1023) / 1024)         // 391 part-role blocks
#define CONVB 128                                    // convert-role blocks appended to part grid

// bf16 RNE helpers (manual, deterministic)
__device__ __forceinline__ unsigned int f2bf(float f) {
    unsigned int b = __float_as_uint(f);
    return (b + 0x7fffu + ((b >> 16) & 1u)) >> 16;
}
__device__ __forceinline__ float bf2f_lo(unsigned int packed) {
    return __uint_as_float(packed << 16);
}
__device__ __forceinline__ float bf2f_hi(unsigned int packed) {
    return __uint_as_float(packed & 0xffff0000u);
}

// ---------------- phase P (+ fused convert) -----------------------------------
// Blocks [0,PBLOCKS): partition edges into 128 group buckets (1 KB LDS, so the
// fused convert blocks are NOT occupancy-limited — the R13 mistake was hosting
// convert in the 54 KB-LDS group kernel).
// Blocks [PBLOCKS, PBLOCKS+CONVB): grid-stride convert x(f32) -> xh(bf16);
// part is atomic-bound (~1 TB/s), so this streaming traffic overlaps ~free.
__global__ __launch_bounds__(1024) void part_conv_kernel(const int* __restrict__ dst,
                                                         const int* __restrict__ src,
                                                         const float* __restrict__ w,
                                                         int* __restrict__ gcur,
                                                         int2* __restrict__ bkt,
                                                         const float* __restrict__ x,
                                                         unsigned int* __restrict__ xh_u32) {
    if (blockIdx.x >= PBLOCKS) {
        // ---- convert role ----
        const int n8 = NNODES * DFEAT / 8;
        int i = (blockIdx.x - PBLOCKS) * 1024 + threadIdx.x;
        const int stride = CONVB * 1024;
        for (; i < n8; i += stride) {
            float4 a = ((const float4*)x)[i * 2 + 0];
            float4 b = ((const float4*)x)[i * 2 + 1];
            uint4 o;
            o.x = f2bf(a.x) | (f2bf(a.y) << 16);
            o.y = f2bf(a.z) | (f2bf(a.w) << 16);
            o.z = f2bf(b.x) | (f2bf(b.y) << 16);
            o.w = f2bf(b.z) | (f2bf(b.w) << 16);
            ((uint4*)xh_u32)[i] = o;
        }
        return;
    }
    // ---- part role ----
    __shared__ int lhist[NG];
    __shared__ int lbase[NG];
    const int n4 = NEDGES / 4;
    int i = blockIdx.x * blockDim.x + threadIdx.x;
    bool active = (i < n4);
    int4 d4 = make_int4(0, 0, 0, 0);
    int4 s4 = make_int4(0, 0, 0, 0);
    float4 w4 = make_float4(0.f, 0.f, 0.f, 0.f);
    if (active) {
        d4 = ((const int4*)dst)[i];
        s4 = ((const int4*)src)[i];
        w4 = ((const float4*)w)[i];
    }
    if (threadIdx.x < NG) lhist[threadIdx.x] = 0;
    __syncthreads();
    int dv[4] = {d4.x, d4.y, d4.z, d4.w};
    int sv[4] = {s4.x, s4.y, s4.z, s4.w};
    float wv[4] = {w4.x, w4.y, w4.z, w4.w};
    int gk[4], slot[4];
    #pragma unroll
    for (int k = 0; k < 4; ++k) {
        gk[k] = dv[k] / GSPAN;
        slot[k] = active ? atomicAdd(&lhist[gk[k]], 1) : 0;
    }
    __syncthreads();
    if (threadIdx.x < NG)
        lbase[threadIdx.x] = atomicAdd(&gcur[threadIdx.x], lhist[threadIdx.x]);
    __syncthreads();
    if (active) {
        #pragma unroll
        for (int k = 0; k < 4; ++k) {
            int g = gk[k];
            int dst_local = dv[k] - g * GSPAN;       // < 782, fits 10 bits
            int idx = g * GCAP + lbase[g] + slot[k];
            bkt[idx] = make_int2(sv[k] | (dst_local << 17), __float_as_int(wv[k]));
        }
    }
}

// ---------------- phase G: per-group hist + scan + scatter --------------------
// 128 blocks x 1024 threads. Group's 782 row counters in LDS: histogram (LDS
// atomics), 1024-wide scan (writes rowptr END pointers, no global atomics),
// scatter with LDS cursors into the group's ~100 KB csr slice (L2-resident).
__global__ __launch_bounds__(1024) void group_kernel(const int2* __restrict__ bkt,
                                                     const int* __restrict__ gcur,
                                                     int* __restrict__ rowptr,
                                                     int2* __restrict__ csr_sw) {
    __shared__ int h[GSPAN];          // hist -> cursor (global positions)
    __shared__ int scanbuf[1024];
    __shared__ int sh_gstart;
    int g = blockIdx.x;
    int tid = threadIdx.x;
    if (tid == 0) {
        int s = 0;
        for (int i = 0; i < g; ++i) s += gcur[i];
        sh_gstart = s;
    }
    if (tid < GSPAN) h[tid] = 0;
    __syncthreads();
    int n = gcur[g];
    const int2* b = bkt + (size_t)g * GCAP;
    for (int j = tid; j < n; j += 1024) {
        atomicAdd(&h[((unsigned)b[j].x) >> 17], 1);
    }
    __syncthreads();
    int v = (tid < GSPAN) ? h[tid] : 0;
    scanbuf[tid] = v;
    __syncthreads();
    for (int off = 1; off < 1024; off <<= 1) {
        int u = (tid >= off) ? scanbuf[tid - off] : 0;
        __syncthreads();
        scanbuf[tid] += u;
        __syncthreads();
    }
    int gstart = sh_gstart;
    int incl = scanbuf[tid];
    if (tid < GSPAN) {
        h[tid] = gstart + incl - v;                  // cursor = row start (global)
        int node = g * GSPAN + tid;
        if (node < NNODES) rowptr[node] = gstart + incl;  // END pointer
    }
    __syncthreads();
    for (int j = tid; j < n; j += 1024) {
        int2 rec = b[j];
        int dl = ((unsigned)rec.x) >> 17;
        int pos = atomicAdd(&h[dl], 1);
        csr_sw[pos] = make_int2(rec.x & 0x1FFFF, rec.y);
    }
}

// ---------------- aggregation ----------------
// After build: row t spans [ t ? rowptr[t-1] : 0 , rowptr[t] ).

__device__ __forceinline__ void agg_row_bf16(const unsigned int* __restrict__ xh,
                                             const int2* __restrict__ csr_sw,
                                             int beg, int end, int lane,
                                             float2& acc) {
    for (int base = beg; base < end; base += 64) {
        int cnt = end - base; if (cnt > 64) cnt = 64;
        int2 sw = make_int2(0, 0);
        if (lane < cnt) sw = csr_sw[base + lane];
        int   my_s = sw.x;
        float my_w = __int_as_float(sw.y);
        int d = 0;
        for (; d + 8 <= cnt; d += 8) {
            int s[8]; float wv[8]; unsigned int v[8];
            #pragma unroll
            for (int k = 0; k < 8; ++k) {
                s[k]  = __shfl(my_s, d + k);
                wv[k] = __shfl(my_w, d + k);
            }
            #pragma unroll
            for (int k = 0; k < 8; ++k) v[k] = xh[(size_t)s[k] * 64 + lane];
            #pragma unroll
            for (int k = 0; k < 8; ++k) {
                acc.x += bf2f_lo(v[k]) * wv[k];
                acc.y += bf2f_hi(v[k]) * wv[k];
            }
        }
        for (; d + 4 <= cnt; d += 4) {
            int s[4]; float wv[4]; unsigned int v[4];
            #pragma unroll
            for (int k = 0; k < 4; ++k) {
                s[k]  = __shfl(my_s, d + k);
                wv[k] = __shfl(my_w, d + k);
            }
            #pragma unroll
            for (int k = 0; k < 4; ++k) v[k] = xh[(size_t)s[k] * 64 + lane];
            #pragma unroll
            for (int k = 0; k < 4; ++k) {
                acc.x += bf2f_lo(v[k]) * wv[k];
                acc.y += bf2f_hi(v[k]) * wv[k];
            }
        }
        for (; d < cnt; ++d) {
            int   s = __shfl(my_s, d);
            float wv = __shfl(my_w, d);
            unsigned int v = xh[(size_t)s * 64 + lane];
            acc.x += bf2f_lo(v) * wv;
            acc.y += bf2f_hi(v) * wv;
        }
    }
}

// hop 1: x1h[n] = bf16( xh[n] + sum_e xh[src_e] * w_e )
__global__ __launch_bounds__(256) void agg1_kernel(const unsigned int* __restrict__ xh,
                                                   const int2* __restrict__ csr_sw,
                                                   const int* __restrict__ rowptr,
                                                   unsigned int* __restrict__ x1h) {
    int gid = blockIdx.x * blockDim.x + threadIdx.x;
    int node = gid >> 6;
    if (node >= NNODES) return;
    int lane = threadIdx.x & 63;
    int beg = node ? rowptr[node - 1] : 0;
    int end = rowptr[node];
    unsigned int r = xh[(size_t)node * 64 + lane];   // residual
    float2 acc = make_float2(bf2f_lo(r), bf2f_hi(r));
    agg_row_bf16(xh, csr_sw, beg, end, lane, acc);
    x1h[(size_t)node * 64 + lane] = f2bf(acc.x) | (f2bf(acc.y) << 16);
}

// hop 2: out[row] = x1h[sel] + sum_e x1h[src_e] * w_e   (f32 output)
__global__ __launch_bounds__(256) void agg2_kernel(const unsigned int* __restrict__ x1h,
                                                   const int2* __restrict__ csr_sw,
                                                   const int* __restrict__ rowptr,
                                                   const int* __restrict__ sel,
                                                   float* __restrict__ out) {
    int gid = blockIdx.x * blockDim.x + threadIdx.x;
    int row = gid >> 6;
    if (row >= NPOOL) return;
    int lane = threadIdx.x & 63;
    int node = sel[row];
    int beg = node ? rowptr[node - 1] : 0;
    int end = rowptr[node];
    unsigned int r = x1h[(size_t)node * 64 + lane];  // residual
    float2 acc = make_float2(bf2f_lo(r), bf2f_hi(r));
    agg_row_bf16(x1h, csr_sw, beg, end, lane, acc);
    ((float2*)out)[(size_t)row * 64 + lane] = acc;
}

// ---------------- launch ----------------

extern "C" void kernel_launch(void* const* d_in, const int* in_sizes, int n_in,
                              void* d_out, int out_size, void* d_ws, size_t ws_size,
                              hipStream_t stream) {
    const float* x         = (const float*)d_in[0];            // [NNODES, DFEAT]
    const float* edge_attr = (const float*)d_in[1];            // [NEDGES]
    const int*   edge_idx  = (const int*)d_in[2];              // [2, NEDGES]
    const int*   sel       = (const int*)d_in[3];              // [NPOOL]
    const int*   src = edge_idx;
    const int*   dst = edge_idx + NEDGES;
    float* out = (float*)d_out;

    // workspace layout: 25.6 + 25.6 + 0.4 + 12.8 + tiny = 64.4 MB (proven budget)
    char* ws = (char*)d_ws;
    unsigned int* xh  = (unsigned int*)ws;  ws += (size_t)NNODES * 64 * sizeof(unsigned int); // 25.6 MB
    char* scratch = ws;                     ws += (size_t)NNODES * 64 * sizeof(unsigned int); // 25.6 MB (x1h)
    int*   rowptr   = (int*)ws;    ws += (size_t)NNODES * sizeof(int);            // 0.4 MB
    int2*  csr_sw   = (int2*)ws;   ws += (size_t)NEDGES * sizeof(int2);           // 12.8 MB
    int*   gcur     = (int*)ws;    ws += (size_t)NG * sizeof(int);

    // bucket scratch aliases x1h (buckets dead before agg1 writes x1h)
    unsigned int* x1h = (unsigned int*)scratch;
    int2* bkt = (int2*)scratch;                                  // 128*14080*8B = 14.4 MB

    hipMemsetAsync(gcur, 0, (size_t)NG * sizeof(int), stream);

    // 1) phase P (+ fused convert; part role has only 1 KB LDS)
    part_conv_kernel<<<PBLOCKS + CONVB, 1024, 0, stream>>>(dst, src, edge_attr,
                                                           gcur, bkt, x, xh);
    // 2) phase G: per-group LDS hist + scan + scatter (zero global atomics)
    group_kernel<<<NG, 1024, 0, stream>>>(bkt, gcur, rowptr, csr_sw);

    // 3) hop 1 (all nodes), bf16 gather, bf16 store
    {
        long long threads = (long long)NNODES * 64;
        int blocks = (int)((threads + 255) / 256);
        agg1_kernel<<<blocks, 256, 0, stream>>>(xh, csr_sw, rowptr, x1h);
    }
    // 4) hop 2 (selected rows only), bf16 gather, f32 out
    {
        long long threads = (long long)NPOOL * 64;
        int blocks = (int)((threads + 255) / 256);
        agg2_kernel<<<blocks, 256, 0, stream>>>(x1h, csr_sw, rowptr, sel, out);
    }
}

// Round 15
// 132.364 us; speedup vs baseline: 1.1652x; 1.0397x over previous
//
#include <hip/hip_runtime.h>

#define NNODES 100000
#define NEDGES 1600000
#define DFEAT  128
#define NPOOL  25000

#define NG 128                                       // partition groups
#define GSPAN ((NNODES + NG - 1) / NG)               // 782 nodes per group (128*782=100096)
#define GCAP 14080                                   // per-group bucket cap (E=12500, sigma~111 -> 14 sigma)
#define PBLOCKS ((NEDGES / 4 + 1023) / 1024)         // 391 part-role blocks
#define CONVB 128                                    // convert-role blocks appended to part grid

// bf16 RNE helpers (manual, deterministic)
__device__ __forceinline__ unsigned int f2bf(float f) {
    unsigned int b = __float_as_uint(f);
    return (b + 0x7fffu + ((b >> 16) & 1u)) >> 16;
}
__device__ __forceinline__ float bf2f_lo(unsigned int packed) {
    return __uint_as_float(packed << 16);
}
__device__ __forceinline__ float bf2f_hi(unsigned int packed) {
    return __uint_as_float(packed & 0xffff0000u);
}

// ---------------- phase P (+ fused convert) -----------------------------------
// Part role: partition 4096 edges/block into 128 group buckets with LDS-staged
// ORDERED write-out: records staged group-major in LDS (32 KB), then swept
// linearly to global so consecutive threads write consecutive addresses within
// each group run -> full-line stores (~1.1x write amp vs 5x scattered).
// Convert role (blocks >= PBLOCKS): grid-stride x(f32) -> xh(bf16); overlaps.
__global__ __launch_bounds__(1024) void part_conv_kernel(const int* __restrict__ dst,
                                                         const int* __restrict__ src,
                                                         const float* __restrict__ w,
                                                         int* __restrict__ gcur,
                                                         int2* __restrict__ bkt,
                                                         const float* __restrict__ x,
                                                         unsigned int* __restrict__ xh_u32) {
    if (blockIdx.x >= PBLOCKS) {
        // ---- convert role ----
        const int n8 = NNODES * DFEAT / 8;
        int i = (blockIdx.x - PBLOCKS) * 1024 + threadIdx.x;
        const int stride = CONVB * 1024;
        for (; i < n8; i += stride) {
            float4 a = ((const float4*)x)[i * 2 + 0];
            float4 b = ((const float4*)x)[i * 2 + 1];
            uint4 o;
            o.x = f2bf(a.x) | (f2bf(a.y) << 16);
            o.y = f2bf(a.z) | (f2bf(a.w) << 16);
            o.z = f2bf(b.x) | (f2bf(b.y) << 16);
            o.w = f2bf(b.z) | (f2bf(b.w) << 16);
            ((uint4*)xh_u32)[i] = o;
        }
        return;
    }
    // ---- part role ----
    __shared__ int lhist[NG];                 // per-group counts
    __shared__ int loff[NG];                  // staging start per group
    __shared__ int lcur[NG];                  // staging cursor per group
    __shared__ int lbase[NG];                 // reserved global run base
    __shared__ int sc[NG];                    // scan scratch
    __shared__ int2 stage[4096];              // 32 KB staged records
    __shared__ unsigned char sgrp[4096];      // group tag per staged record
    const int n4 = NEDGES / 4;
    int tid = threadIdx.x;
    int i = blockIdx.x * blockDim.x + tid;
    bool active = (i < n4);
    int4 d4 = make_int4(0, 0, 0, 0);
    int4 s4 = make_int4(0, 0, 0, 0);
    float4 w4 = make_float4(0.f, 0.f, 0.f, 0.f);
    if (active) {
        d4 = ((const int4*)dst)[i];
        s4 = ((const int4*)src)[i];
        w4 = ((const float4*)w)[i];
    }
    if (tid < NG) lhist[tid] = 0;
    __syncthreads();
    int dv[4] = {d4.x, d4.y, d4.z, d4.w};
    int sv[4] = {s4.x, s4.y, s4.z, s4.w};
    float wv[4] = {w4.x, w4.y, w4.z, w4.w};
    int gk[4];
    #pragma unroll
    for (int k = 0; k < 4; ++k) {
        gk[k] = dv[k] / GSPAN;
        if (active) atomicAdd(&lhist[gk[k]], 1);     // pass 1: count
    }
    __syncthreads();
    // 128-wide inclusive scan of counts -> staging offsets; reserve global runs
    if (tid < NG) sc[tid] = lhist[tid];
    __syncthreads();
    for (int off = 1; off < NG; off <<= 1) {
        int u = (tid >= off && tid < NG) ? sc[tid - off] : 0;
        __syncthreads();
        if (tid < NG) sc[tid] += u;
        __syncthreads();
    }
    if (tid < NG) {
        int excl = sc[tid] - lhist[tid];
        loff[tid] = excl;
        lcur[tid] = excl;
        lbase[tid] = atomicAdd(&gcur[tid], lhist[tid]);
    }
    __syncthreads();
    // pass 2: scatter into LDS staging (group-major layout)
    if (active) {
        #pragma unroll
        for (int k = 0; k < 4; ++k) {
            int g = gk[k];
            int dst_local = dv[k] - g * GSPAN;       // < 782, fits 10 bits
            int p = atomicAdd(&lcur[g], 1);
            stage[p] = make_int2(sv[k] | (dst_local << 17), __float_as_int(wv[k]));
            sgrp[p] = (unsigned char)g;
        }
    }
    __syncthreads();
    // ordered sweep: consecutive threads -> consecutive global addresses per run
    int total = loff[NG - 1] + lhist[NG - 1];
    for (int j = tid; j < total; j += 1024) {
        int g = sgrp[j];
        bkt[(size_t)g * GCAP + lbase[g] + (j - loff[g])] = stage[j];
    }
}

// ---------------- phase G: per-group hist + scan + scatter --------------------
// 128 blocks x 1024 threads. Group's 782 row counters in LDS: histogram (LDS
// atomics), 1024-wide scan (writes rowptr END pointers, no global atomics),
// scatter with LDS cursors into the group's ~100 KB csr slice (L2-resident).
__global__ __launch_bounds__(1024) void group_kernel(const int2* __restrict__ bkt,
                                                     const int* __restrict__ gcur,
                                                     int* __restrict__ rowptr,
                                                     int2* __restrict__ csr_sw) {
    __shared__ int h[GSPAN];          // hist -> cursor (global positions)
    __shared__ int scanbuf[1024];
    __shared__ int sh_gstart;
    int g = blockIdx.x;
    int tid = threadIdx.x;
    if (tid == 0) {
        int s = 0;
        for (int i = 0; i < g; ++i) s += gcur[i];
        sh_gstart = s;
    }
    if (tid < GSPAN) h[tid] = 0;
    __syncthreads();
    int n = gcur[g];
    const int2* b = bkt + (size_t)g * GCAP;
    for (int j = tid; j < n; j += 1024) {
        atomicAdd(&h[((unsigned)b[j].x) >> 17], 1);
    }
    __syncthreads();
    int v = (tid < GSPAN) ? h[tid] : 0;
    scanbuf[tid] = v;
    __syncthreads();
    for (int off = 1; off < 1024; off <<= 1) {
        int u = (tid >= off) ? scanbuf[tid - off] : 0;
        __syncthreads();
        scanbuf[tid] += u;
        __syncthreads();
    }
    int gstart = sh_gstart;
    int incl = scanbuf[tid];
    if (tid < GSPAN) {
        h[tid] = gstart + incl - v;                  // cursor = row start (global)
        int node = g * GSPAN + tid;
        if (node < NNODES) rowptr[node] = gstart + incl;  // END pointer
    }
    __syncthreads();
    for (int j = tid; j < n; j += 1024) {
        int2 rec = b[j];
        int dl = ((unsigned)rec.x) >> 17;
        int pos = atomicAdd(&h[dl], 1);
        csr_sw[pos] = make_int2(rec.x & 0x1FFFF, rec.y);
    }
}

// ---------------- aggregation ----------------
// After build: row t spans [ t ? rowptr[t-1] : 0 , rowptr[t] ).

__device__ __forceinline__ void agg_row_bf16(const unsigned int* __restrict__ xh,
                                             const int2* __restrict__ csr_sw,
                                             int beg, int end, int lane,
                                             float2& acc) {
    for (int base = beg; base < end; base += 64) {
        int cnt = end - base; if (cnt > 64) cnt = 64;
        int2 sw = make_int2(0, 0);
        if (lane < cnt) sw = csr_sw[base + lane];
        int   my_s = sw.x;
        float my_w = __int_as_float(sw.y);
        int d = 0;
        for (; d + 8 <= cnt; d += 8) {
            int s[8]; float wv[8]; unsigned int v[8];
            #pragma unroll
            for (int k = 0; k < 8; ++k) {
                s[k]  = __shfl(my_s, d + k);
                wv[k] = __shfl(my_w, d + k);
            }
            #pragma unroll
            for (int k = 0; k < 8; ++k) v[k] = xh[(size_t)s[k] * 64 + lane];
            #pragma unroll
            for (int k = 0; k < 8; ++k) {
                acc.x += bf2f_lo(v[k]) * wv[k];
                acc.y += bf2f_hi(v[k]) * wv[k];
            }
        }
        for (; d + 4 <= cnt; d += 4) {
            int s[4]; float wv[4]; unsigned int v[4];
            #pragma unroll
            for (int k = 0; k < 4; ++k) {
                s[k]  = __shfl(my_s, d + k);
                wv[k] = __shfl(my_w, d + k);
            }
            #pragma unroll
            for (int k = 0; k < 4; ++k) v[k] = xh[(size_t)s[k] * 64 + lane];
            #pragma unroll
            for (int k = 0; k < 4; ++k) {
                acc.x += bf2f_lo(v[k]) * wv[k];
                acc.y += bf2f_hi(v[k]) * wv[k];
            }
        }
        for (; d < cnt; ++d) {
            int   s = __shfl(my_s, d);
            float wv = __shfl(my_w, d);
            unsigned int v = xh[(size_t)s * 64 + lane];
            acc.x += bf2f_lo(v) * wv;
            acc.y += bf2f_hi(v) * wv;
        }
    }
}

// hop 1: x1h[n] = bf16( xh[n] + sum_e xh[src_e] * w_e )
__global__ __launch_bounds__(256) void agg1_kernel(const unsigned int* __restrict__ xh,
                                                   const int2* __restrict__ csr_sw,
                                                   const int* __restrict__ rowptr,
                                                   unsigned int* __restrict__ x1h) {
    int gid = blockIdx.x * blockDim.x + threadIdx.x;
    int node = gid >> 6;
    if (node >= NNODES) return;
    int lane = threadIdx.x & 63;
    int beg = node ? rowptr[node - 1] : 0;
    int end = rowptr[node];
    unsigned int r = xh[(size_t)node * 64 + lane];   // residual
    float2 acc = make_float2(bf2f_lo(r), bf2f_hi(r));
    agg_row_bf16(xh, csr_sw, beg, end, lane, acc);
    x1h[(size_t)node * 64 + lane] = f2bf(acc.x) | (f2bf(acc.y) << 16);
}

// hop 2: out[row] = x1h[sel] + sum_e x1h[src_e] * w_e   (f32 output)
__global__ __launch_bounds__(256) void agg2_kernel(const unsigned int* __restrict__ x1h,
                                                   const int2* __restrict__ csr_sw,
                                                   const int* __restrict__ rowptr,
                                                   const int* __restrict__ sel,
                                                   float* __restrict__ out) {
    int gid = blockIdx.x * blockDim.x + threadIdx.x;
    int row = gid >> 6;
    if (row >= NPOOL) return;
    int lane = threadIdx.x & 63;
    int node = sel[row];
    int beg = node ? rowptr[node - 1] : 0;
    int end = rowptr[node];
    unsigned int r = x1h[(size_t)node * 64 + lane];  // residual
    float2 acc = make_float2(bf2f_lo(r), bf2f_hi(r));
    agg_row_bf16(x1h, csr_sw, beg, end, lane, acc);
    ((float2*)out)[(size_t)row * 64 + lane] = acc;
}

// ---------------- launch ----------------

extern "C" void kernel_launch(void* const* d_in, const int* in_sizes, int n_in,
                              void* d_out, int out_size, void* d_ws, size_t ws_size,
                              hipStream_t stream) {
    const float* x         = (const float*)d_in[0];            // [NNODES, DFEAT]
    const float* edge_attr = (const float*)d_in[1];            // [NEDGES]
    const int*   edge_idx  = (const int*)d_in[2];              // [2, NEDGES]
    const int*   sel       = (const int*)d_in[3];              // [NPOOL]
    const int*   src = edge_idx;
    const int*   dst = edge_idx + NEDGES;
    float* out = (float*)d_out;

    // workspace layout: 25.6 + 25.6 + 0.4 + 12.8 + tiny = 64.4 MB (proven budget)
    char* ws = (char*)d_ws;
    unsigned int* xh  = (unsigned int*)ws;  ws += (size_t)NNODES * 64 * sizeof(unsigned int); // 25.6 MB
    char* scratch = ws;                     ws += (size_t)NNODES * 64 * sizeof(unsigned int); // 25.6 MB (x1h)
    int*   rowptr   = (int*)ws;    ws += (size_t)NNODES * sizeof(int);            // 0.4 MB
    int2*  csr_sw   = (int2*)ws;   ws += (size_t)NEDGES * sizeof(int2);           // 12.8 MB
    int*   gcur     = (int*)ws;    ws += (size_t)NG * sizeof(int);

    // bucket scratch aliases x1h (buckets dead before agg1 writes x1h)
    unsigned int* x1h = (unsigned int*)scratch;
    int2* bkt = (int2*)scratch;                                  // 128*14080*8B = 14.4 MB

    hipMemsetAsync(gcur, 0, (size_t)NG * sizeof(int), stream);

    // 1) phase P (+ fused convert): LDS-staged ordered bucket writes
    part_conv_kernel<<<PBLOCKS + CONVB, 1024, 0, stream>>>(dst, src, edge_attr,
                                                           gcur, bkt, x, xh);
    // 2) phase G: per-group LDS hist + scan + scatter (zero global atomics)
    group_kernel<<<NG, 1024, 0, stream>>>(bkt, gcur, rowptr, csr_sw);

    // 3) hop 1 (all nodes), bf16 gather, bf16 store
    {
        long long threads = (long long)NNODES * 64;
        int blocks = (int)((threads + 255) / 256);
        agg1_kernel<<<blocks, 256, 0, stream>>>(xh, csr_sw, rowptr, x1h);
    }
    // 4) hop 2 (selected rows only), bf16 gather, f32 out
    {
        long long threads = (long long)NPOOL * 64;
        int blocks = (int)((threads + 255) / 256);
        agg2_kernel<<<blocks, 256, 0, stream>>>(x1h, csr_sw, rowptr, sel, out);
    }
}